// Round 6
// baseline (633.411 us; speedup 1.0000x reference)
//
#include <hip/hip_runtime.h>
#include <math.h>

#define B_SZ 24
#define D_EMBD 512
#define N_CLS 10000
#define CC 256
#define HH 196

#define S_SCALE 64.0f
#define COS_M 0.9004471023526769f
#define SIN_M 0.43496553411123023f
#define TH_C (-0.9004471023526769f)
#define MM_C 0.19573449035005357f
#define KSC 14.4269504088896f          /* 10*log2(e) */
#define C2E 0.0693147180559945f        /* eps*ln2 */

typedef short bfrag8 __attribute__((ext_vector_type(8)));
typedef float facc4 __attribute__((ext_vector_type(4)));

#if __has_builtin(__builtin_amdgcn_exp2f)
#define EXP2F(x) __builtin_amdgcn_exp2f(x)
#else
#define EXP2F(x) exp2f(x)
#endif
#if __has_builtin(__builtin_amdgcn_logf)
#define LOG2F(x) __builtin_amdgcn_logf(x)
#else
#define LOG2F(x) __log2f(x)
#endif

__device__ inline unsigned short f2bf_rne(float x) {
    union { float f; unsigned u; } cv; cv.f = x;
    unsigned r = cv.u + 0x7FFFu + ((cv.u >> 16) & 1u);
    return (unsigned short)(r >> 16);
}
__device__ inline float bf2f(unsigned short h) {
    union { unsigned u; float f; } cv; cv.u = ((unsigned)h) << 16; return cv.f;
}
__device__ inline float bflo(unsigned u) {
    union { unsigned x; float f; } c; c.x = u << 16; return c.f;
}
__device__ inline float bfhi(unsigned u) {
    union { unsigned x; float f; } c; c.x = u & 0xffff0000u; return c.f;
}
__device__ inline unsigned packbf(float a, float b) {
    return (unsigned)f2bf_rne(a) | ((unsigned)f2bf_rne(b) << 16);
}
// XOR bank swizzle: physical 8-short chunk for (row, logical chunk q)
__device__ inline int swz(int row, int q) {
    return (q ^ (row & 3) ^ ((row >> 2) & 3)) & 3;
}

// ================= Launch 1: pairs (quarter-GEMM + in-reg Sinkhorn) + emb gram =================
// blocks 0..275: one (a<b) pair, 512 thr (8 waves). Quarter-tiled 256x256 GEMM (acc 32 regs),
//   E = 2^(rm - Ceps2) packed bf16 in 64 VGPRs, Sinkhorn in registers/LDS.
//   __launch_bounds__(512, 2): 2nd arg is min BLOCKS/CU (CUDA semantics; measured R4/R5:
//   arg=4 -> 64 VGPR cap + spill, arg=2 -> 128 VGPR budget). 2 blocks/CU co-resident.
// blocks 276..347: 24x24 emb-cosine gram, 8 pairs/block. Block 276 zeros Dmat diag.
__global__ __launch_bounds__(512, 2) void k_pairs2(const float* __restrict__ emb,
        const float* __restrict__ conv, float* __restrict__ dists,
        float* __restrict__ Dmat) {
    const int t = threadIdx.x;
    const int bid = blockIdx.x;

    if (bid >= 276) {
        // ---- emb gram path (no barriers) ----
        int l = t & 63, w16 = t >> 6;
        if (bid == 276 && t < B_SZ) Dmat[t * B_SZ + t] = 0.f;
        int pid = (bid - 276) * 8 + w16;
        if (pid >= B_SZ * B_SZ) return;
        int i = pid / B_SZ, j = pid - (pid / B_SZ) * B_SZ;
        float sij = 0.f, sii = 0.f, sjj = 0.f;
        #pragma unroll
        for (int u = 0; u < 8; ++u) {
            float vi = emb[i*D_EMBD + u*64 + l];
            float vj = emb[j*D_EMBD + u*64 + l];
            sij = fmaf(vi, vj, sij); sii = fmaf(vi, vi, sii); sjj = fmaf(vj, vj, sjj);
        }
        #pragma unroll
        for (int o = 1; o < 64; o <<= 1) {
            sij += __shfl_xor(sij, o, 64);
            sii += __shfl_xor(sii, o, 64);
            sjj += __shfl_xor(sjj, o, 64);
        }
        if (l == 0) dists[pid] = sij * rsqrtf(sii * sjj);
        return;
    }

    __shared__ __align__(16) unsigned short AhS[128*32];   // 8 KB each
    __shared__ __align__(16) unsigned short AlS[128*32];
    __shared__ __align__(16) unsigned short BhS[128*32];
    __shared__ __align__(16) unsigned short BlS[128*32];
    __shared__ __align__(16) float na_s[256];
    __shared__ float nb_s[256];
    __shared__ float rowred[1024];        // quarter: [4][128]; sinkhorn: [4][256]
    __shared__ __align__(16) float rmq[512];   // [ch][global row]
    __shared__ __align__(16) float rm_l[256];
    __shared__ __align__(16) float z_l[256];
    __shared__ float g_l[256];
    __shared__ float colred[512];         // [2][256]
    __shared__ float wredF[4], wredG[4], wredD[8];

    const int w = t >> 6;                  // 0..7
    const int wr2 = w >> 2;                // 0..1 : 64-row group within 128
    const int wc2 = w & 3;                 // 0..3 : 32-col group within 128
    const int q = (t >> 4) & 3, c0 = t & 15;
    const int sn = t >> 2, sch = t & 3;    // staging: row 0..127, 8-el chunk

    // pair index -> (a, b), a < b
    int rem = bid, a = 0;
    while (rem >= 23 - a) { rem -= 23 - a; ++a; }
    int b = a + 1 + rem;
    const float* xa = conv + a*CC*HH;
    const float* xb = conv + b*CC*HH;

    unsigned ue[64];                       // packed bf16 E, 128 elements

    const int istar = ((c0&1)<<3) | ((c0&2)<<1) | ((c0&4)>>1) | ((c0&8)>>3);
    const int rloc_star = wr2*64 + (istar>>2)*16 + q*4 + (istar&3);  // 0..127

    // ---- 4 quarter GEMMs: (rh, ch) over rows rh*128, cols ch*128 ----
    #pragma unroll
    for (int qq = 0; qq < 4; ++qq) {
        const int rh = qq >> 1, ch = qq & 1;
        const float* xA = xa + rh*128*HH;
        const float* xB = xb + ch*128*HH;
        facc4 acc[4][2];
        #pragma unroll
        for (int i = 0; i < 4; ++i) { acc[i][0] = (facc4){0,0,0,0}; acc[i][1] = (facc4){0,0,0,0}; }
        float pqa = 0.f, pqb = 0.f;

        const int sws = swz(sn, sch);      // swizzled physical chunk for staging store

        #pragma unroll 1
        for (int ks = 0; ks < 224; ks += 32) {
            __syncthreads();
            const int k0 = ks + sch*8;
            #pragma unroll
            for (int p = 0; p < 2; ++p) {
                const float* src = (p ? xB : xA) + sn*HH + k0;
                float v[8];
                if (k0 + 8 <= HH) {
                    const float4* s4 = (const float4*)src;
                    float4 u0 = s4[0], u1 = s4[1];
                    v[0]=u0.x; v[1]=u0.y; v[2]=u0.z; v[3]=u0.w;
                    v[4]=u1.x; v[5]=u1.y; v[6]=u1.z; v[7]=u1.w;
                } else {
                    #pragma unroll
                    for (int j = 0; j < 8; ++j) v[j] = (k0 + j < HH) ? src[j] : 0.f;
                }
                float ps = 0.f;
                union { unsigned short s[8]; bfrag8 v8; } uh, ul;
                #pragma unroll
                for (int j = 0; j < 8; ++j) {
                    ps = fmaf(v[j], v[j], ps);
                    unsigned short hb = f2bf_rne(v[j]);
                    uh.s[j] = hb;
                    ul.s[j] = f2bf_rne(v[j] - bf2f(hb));
                }
                if (p) { if (rh == 0) pqb += ps; }
                else   { if (ch == 0) pqa += ps; }
                *(bfrag8*)&((p ? BhS : AhS)[sn*32 + sws*8]) = uh.v8;
                *(bfrag8*)&((p ? BlS : AlS)[sn*32 + sws*8]) = ul.v8;
            }
            __syncthreads();
            bfrag8 bh2[2], bl2[2];
            #pragma unroll
            for (int tj = 0; tj < 2; ++tj) {
                int col = wc2*32 + tj*16 + c0;
                int cof = col*32 + swz(col, q)*8;
                bh2[tj] = *(const bfrag8*)&BhS[cof];
                bl2[tj] = *(const bfrag8*)&BlS[cof];
            }
            #pragma unroll
            for (int ti = 0; ti < 4; ++ti) {
                int row = wr2*64 + ti*16 + c0;
                int rof = row*32 + swz(row, q)*8;
                bfrag8 ah = *(const bfrag8*)&AhS[rof];
                bfrag8 al = *(const bfrag8*)&AlS[rof];
                #pragma unroll
                for (int tj = 0; tj < 2; ++tj) {
                    acc[ti][tj] = __builtin_amdgcn_mfma_f32_16x16x32_bf16(ah, bh2[tj], acc[ti][tj], 0, 0, 0);
                    acc[ti][tj] = __builtin_amdgcn_mfma_f32_16x16x32_bf16(ah, bl2[tj], acc[ti][tj], 0, 0, 0);
                    acc[ti][tj] = __builtin_amdgcn_mfma_f32_16x16x32_bf16(al, bh2[tj], acc[ti][tj], 0, 0, 0);
                }
            }
        }
        // point norms (4 lanes per row, lane-adjacent)
        if (ch == 0) {
            pqa += __shfl_xor(pqa, 1, 64); pqa += __shfl_xor(pqa, 2, 64);
            if (sch == 0) na_s[rh*128 + sn] = pqa;
        }
        if (rh == 0) {
            pqb += __shfl_xor(pqb, 1, 64); pqb += __shfl_xor(pqb, 2, 64);
            if (sch == 0) nb_s[ch*128 + sn] = pqb;
        }
        __syncthreads();

        // Ceps2 for the quarter; local row-min over its 128 cols
        facc4 Cv[4][2];
        {
            float nbv[2];
            #pragma unroll
            for (int tj = 0; tj < 2; ++tj) nbv[tj] = nb_s[ch*128 + wc2*32 + tj*16 + c0];
            #pragma unroll
            for (int ti = 0; ti < 4; ++ti) {
                facc4 nav = *(const facc4*)&na_s[rh*128 + wr2*64 + ti*16 + q*4];
                #pragma unroll
                for (int tj = 0; tj < 2; ++tj) {
                    #pragma unroll
                    for (int r = 0; r < 4; ++r) {
                        float d2 = fmaxf(nav[r] + nbv[tj] - 2.f*acc[ti][tj][r], 0.f);
                        Cv[ti][tj][r] = KSC * sqrtf(d2 + 1e-12f);
                    }
                }
            }
        }
        {
            float v16[16];
            #pragma unroll
            for (int ti = 0; ti < 4; ++ti)
                #pragma unroll
                for (int r = 0; r < 4; ++r)
                    v16[ti*4+r] = fminf(Cv[ti][0][r], Cv[ti][1][r]);
            #pragma unroll
            for (int p = 0; p < 4; ++p) {
                const int m = 1 << p, hsz = 8 >> p;
                const bool hi = (c0 >> p) & 1;
                #pragma unroll
                for (int j = 0; j < hsz; ++j) {
                    float mine = hi ? v16[j+hsz] : v16[j];
                    float send = hi ? v16[j] : v16[j+hsz];
                    v16[j] = fminf(mine, __shfl_xor(send, m, 64));
                }
            }
            rowred[wc2*128 + rloc_star] = v16[0];
        }
        __syncthreads();
        if (t < 128) {
            float m = fminf(fminf(rowred[t], rowred[128+t]), fminf(rowred[256+t], rowred[384+t]));
            rmq[ch*256 + rh*128 + t] = m;
        }
        __syncthreads();
        // E_q = 2^(rmq - Ceps2) packed bf16 -> ue[qq*16 ..]
        #pragma unroll
        for (int ti = 0; ti < 4; ++ti) {
            facc4 rmv = *(const facc4*)&rmq[ch*256 + rh*128 + wr2*64 + ti*16 + q*4];
            #pragma unroll
            for (int tj = 0; tj < 2; ++tj) {
                float e0 = EXP2F(rmv[0] - Cv[ti][tj][0]);
                float e1 = EXP2F(rmv[1] - Cv[ti][tj][1]);
                float e2 = EXP2F(rmv[2] - Cv[ti][tj][2]);
                float e3 = EXP2F(rmv[3] - Cv[ti][tj][3]);
                ue[qq*16 + ti*4 + tj*2 + 0] = packbf(e0, e1);
                ue[qq*16 + ti*4 + tj*2 + 1] = packbf(e2, e3);
            }
        }
    }

    // ---- final rm = min over col halves; rescale E exactly (power of 2) ----
    if (t < 256) { rm_l[t] = fminf(rmq[t], rmq[256+t]); g_l[t] = 0.f; }
    if (t < 4) wredG[t] = 0.f;
    __syncthreads();
    #pragma unroll
    for (int rh = 0; rh < 2; ++rh) {
        #pragma unroll
        for (int ti = 0; ti < 4; ++ti) {
            const int rb = rh*128 + wr2*64 + ti*16 + q*4;
            facc4 rmv = *(const facc4*)&rm_l[rb];
            #pragma unroll
            for (int ch = 0; ch < 2; ++ch) {
                facc4 rq = *(const facc4*)&rmq[ch*256 + rb];
                float s0 = EXP2F(rmv[0] - rq[0]);
                float s1 = EXP2F(rmv[1] - rq[1]);
                float s2 = EXP2F(rmv[2] - rq[2]);
                float s3 = EXP2F(rmv[3] - rq[3]);
                #pragma unroll
                for (int tj = 0; tj < 2; ++tj) {
                    const int i0 = (rh*2+ch)*16 + ti*4 + tj*2;
                    unsigned u0 = ue[i0], u1 = ue[i0+1];
                    ue[i0]   = packbf(bflo(u0)*s0, bfhi(u0)*s1);
                    ue[i0+1] = packbf(bflo(u1)*s2, bfhi(u1)*s3);
                }
            }
        }
    }

    // ---- 6 Sinkhorn iterations ----
    #pragma unroll 1
    for (int it = 0; it < 6; ++it) {
        // phase A: row partial sums over this thread's 4 cols
        float Gmax = fmaxf(fmaxf(wredG[0], wredG[1]), fmaxf(wredG[2], wredG[3]));
        float P4[4];
        #pragma unroll
        for (int ch = 0; ch < 2; ++ch)
            #pragma unroll
            for (int tj = 0; tj < 2; ++tj)
                P4[ch*2+tj] = EXP2F(g_l[ch*128 + wc2*32 + tj*16 + c0] - Gmax);
        #pragma unroll
        for (int rh = 0; rh < 2; ++rh) {
            float v16[16];
            #pragma unroll
            for (int ti = 0; ti < 4; ++ti) {
                float s0 = 0.f, s1 = 0.f, s2 = 0.f, s3 = 0.f;
                #pragma unroll
                for (int ch = 0; ch < 2; ++ch)
                    #pragma unroll
                    for (int tj = 0; tj < 2; ++tj) {
                        const int i0 = (rh*2+ch)*16 + ti*4 + tj*2;
                        unsigned u0 = ue[i0], u1 = ue[i0+1];
                        float p = P4[ch*2+tj];
                        s0 = fmaf(bflo(u0), p, s0); s1 = fmaf(bfhi(u0), p, s1);
                        s2 = fmaf(bflo(u1), p, s2); s3 = fmaf(bfhi(u1), p, s3);
                    }
                v16[ti*4+0]=s0; v16[ti*4+1]=s1; v16[ti*4+2]=s2; v16[ti*4+3]=s3;
            }
            #pragma unroll
            for (int p = 0; p < 4; ++p) {
                const int m = 1 << p, hsz = 8 >> p;
                const bool hi = (c0 >> p) & 1;
                #pragma unroll
                for (int j = 0; j < hsz; ++j) {
                    float mine = hi ? v16[j+hsz] : v16[j];
                    float send = hi ? v16[j] : v16[j+hsz];
                    v16[j] = mine + __shfl_xor(send, m, 64);
                }
            }
            rowred[wc2*256 + rh*128 + rloc_star] = v16[0];
        }
        __syncthreads();
        if (t < 256) {
            float s = rowred[t] + rowred[256+t] + rowred[512+t] + rowred[768+t];
            float z = 8.f - Gmax - LOG2F(s);
            z_l[t] = z;
            float m = z;
            #pragma unroll
            for (int o = 1; o < 64; o <<= 1) m = fmaxf(m, __shfl_xor(m, o, 64));
            if ((t & 63) == 0) wredF[t >> 6] = m;
        }
        __syncthreads();
        // phase C: col partial sums over this thread's 32 rows
        float M = fmaxf(fmaxf(wredF[0], wredF[1]), fmaxf(wredF[2], wredF[3]));
        float w4[4] = {0.f, 0.f, 0.f, 0.f};
        #pragma unroll
        for (int rh = 0; rh < 2; ++rh)
            #pragma unroll
            for (int ti = 0; ti < 4; ++ti) {
                facc4 zv = *(const facc4*)&z_l[rh*128 + wr2*64 + ti*16 + q*4];
                float Q0 = EXP2F(zv[0] - M), Q1 = EXP2F(zv[1] - M);
                float Q2 = EXP2F(zv[2] - M), Q3 = EXP2F(zv[3] - M);
                #pragma unroll
                for (int ch = 0; ch < 2; ++ch)
                    #pragma unroll
                    for (int tj = 0; tj < 2; ++tj) {
                        const int i0 = (rh*2+ch)*16 + ti*4 + tj*2;
                        unsigned u0 = ue[i0], u1 = ue[i0+1];
                        float s = w4[ch*2+tj];
                        s = fmaf(bflo(u0), Q0, s); s = fmaf(bfhi(u0), Q1, s);
                        s = fmaf(bflo(u1), Q2, s); s = fmaf(bfhi(u1), Q3, s);
                        w4[ch*2+tj] = s;
                    }
            }
        {   // q-tournament: strides 16, 32; lane q keeps idx = (q&1)*2 + (q>>1)
            #pragma unroll
            for (int p = 0; p < 2; ++p) {
                const int m = 16 << p, hsz = 2 >> p;
                const bool hi = p == 0 ? (q & 1) : ((q >> 1) & 1);
                #pragma unroll
                for (int j = 0; j < hsz; ++j) {
                    float mine = hi ? w4[j+hsz] : w4[j];
                    float send = hi ? w4[j] : w4[j+hsz];
                    w4[j] = mine + __shfl_xor(send, m, 64);
                }
            }
            const int colstar = (q&1)*128 + wc2*32 + (q>>1)*16 + c0;
            colred[wr2*256 + colstar] = w4[0];
        }
        __syncthreads();
        if (t < 256) {
            float s = colred[t] + colred[256+t];
            float G = 8.f - M - LOG2F(s);
            g_l[t] = G;
            float m = G;
            #pragma unroll
            for (int o = 1; o < 64; o <<= 1) m = fmaxf(m, __shfl_xor(m, o, 64));
            if ((t & 63) == 0) wredG[t >> 6] = m;
        }
        __syncthreads();
    }

    // ---- D = sum(T*C): T = 2^(z + G - 16 + log2 E), Ceps2 = rm - log2 E ----
    {
        float G4[4];
        #pragma unroll
        for (int ch = 0; ch < 2; ++ch)
            #pragma unroll
            for (int tj = 0; tj < 2; ++tj)
                G4[ch*2+tj] = g_l[ch*128 + wc2*32 + tj*16 + c0] - 16.f;
        float d = 0.f;
        #pragma unroll
        for (int rh = 0; rh < 2; ++rh)
            #pragma unroll
            for (int ti = 0; ti < 4; ++ti) {
                const int rb = rh*128 + wr2*64 + ti*16 + q*4;
                facc4 zv = *(const facc4*)&z_l[rb];
                facc4 rmv = *(const facc4*)&rm_l[rb];
                #pragma unroll
                for (int ch = 0; ch < 2; ++ch)
                    #pragma unroll
                    for (int tj = 0; tj < 2; ++tj) {
                        const int i0 = (rh*2+ch)*16 + ti*4 + tj*2;
                        unsigned u0 = ue[i0], u1 = ue[i0+1];
                        float gb = G4[ch*2+tj];
                        float e, lE;
                        e = fmaxf(bflo(u0), 1e-38f); lE = LOG2F(e);
                        d = fmaf(EXP2F(zv[0] + gb + lE), rmv[0] - lE, d);
                        e = fmaxf(bfhi(u0), 1e-38f); lE = LOG2F(e);
                        d = fmaf(EXP2F(zv[1] + gb + lE), rmv[1] - lE, d);
                        e = fmaxf(bflo(u1), 1e-38f); lE = LOG2F(e);
                        d = fmaf(EXP2F(zv[2] + gb + lE), rmv[2] - lE, d);
                        e = fmaxf(bfhi(u1), 1e-38f); lE = LOG2F(e);
                        d = fmaf(EXP2F(zv[3] + gb + lE), rmv[3] - lE, d);
                    }
            }
        d *= C2E;
        #pragma unroll
        for (int o = 1; o < 64; o <<= 1) d += __shfl_xor(d, o, 64);
        if ((t & 63) == 0) wredD[w] = d;
        __syncthreads();
        if (t == 0) {
            float s = 0.f;
            #pragma unroll
            for (int i = 0; i < 8; ++i) s += wredD[i];
            Dmat[a*B_SZ + b] = s;
            Dmat[b*B_SZ + a] = s;
        }
    }
}

// ============ Launch 2: arcface (blocks 0..312) + final (block 313) ============
__global__ __launch_bounds__(256) void k_arc_fin(const float* __restrict__ emb,
        const float* __restrict__ kern, const int* __restrict__ label,
        const float* __restrict__ dists, const float* __restrict__ Dmat,
        float* __restrict__ out) {
    const int t = threadIdx.x;
    const int bid = blockIdx.x;

    if (bid == 313) {
        __shared__ float ds[576], Dm[576];
        __shared__ int lab[B_SZ];
        __shared__ float wls[4]; __shared__ int wnp[4], wot[4];
        for (int i = t; i < 576; i += 256) { ds[i] = dists[i]; Dm[i] = Dmat[i]; }
        if (t < B_SZ) lab[t] = label[t];
        __syncthreads();
        int np = 0, ot = 0; float wsum = 0.f;
        for (int idx = t; idx < 24*24*24; idx += 256) {
            int a2 = idx / 576;
            int rest = idx - a2*576;
            int p2 = rest / 24;
            int n2 = rest - p2*24;
            int la = lab[a2];
            if (la == lab[p2] && la != lab[n2]) {
                float diff = ds[a2*24 + n2] - ds[a2*24 + p2];
                if (diff > 0.f) {
                    ++np;
                    float dd = Dm[a2*24 + p2] - Dm[a2*24 + n2];
                    if (dd > 0.f) { ++ot; wsum += dd; }
                }
            }
        }
        #pragma unroll
        for (int o = 1; o < 64; o <<= 1) {
            np += __shfl_xor(np, o, 64);
            ot += __shfl_xor(ot, o, 64);
            wsum += __shfl_xor(wsum, o, 64);
        }
        int w = t >> 6;
        if ((t & 63) == 0) { wnp[w] = np; wot[w] = ot; wls[w] = wsum; }
        __syncthreads();
        if (t == 0) {
            int tnp = wnp[0]+wnp[1]+wnp[2]+wnp[3];
            int tot = wot[0]+wot[1]+wot[2]+wot[3];
            float tws = wls[0]+wls[1]+wls[2]+wls[3];
            int den = tot > 1 ? tot : 1;
            float wl = (tws > 0.f) ? tws / (float)den : 0.f;
            out[240000] = wl;
            out[480001] = (float)tnp;
            out[480002] = (float)tot;
        }
        return;
    }

    __shared__ __align__(16) float es[B_SZ*D_EMBD];
    __shared__ float inv_s[B_SZ];
    __shared__ int lab_s[B_SZ];
    float* part = es;
    float* resb = es + 6400;

    {
        const float4* s4 = (const float4*)emb;
        float4* d4 = (float4*)es;
        for (int i = t; i < (B_SZ*D_EMBD)/4; i += 256) d4[i] = s4[i];
    }
    if (t < B_SZ) lab_s[t] = label[t];
    __syncthreads();
    {
        int l = t & 63, w = t >> 6;
        for (int r = w; r < B_SZ; r += 4) {
            float s = 0.f;
            #pragma unroll
            for (int u = 0; u < 8; ++u) { float v = es[r*D_EMBD + u*64 + l]; s = fmaf(v, v, s); }
            #pragma unroll
            for (int o = 1; o < 64; o <<= 1) s += __shfl_xor(s, o, 64);
            if (l == 0) inv_s[r] = rsqrtf(s);
        }
    }
    __syncthreads();

    const int cc = t & 31, kc = t >> 5;
    int c = bid*32 + cc;
    int cL = c < N_CLS ? c : N_CLS - 1;
    float acc[B_SZ];
    #pragma unroll
    for (int r = 0; r < B_SZ; ++r) acc[r] = 0.f;
    float cn = 0.f;
    const int k0 = kc*64;
    for (int u = 0; u < 16; ++u) {
        int kb = k0 + u*4;
        float kv0 = kern[(kb+0)*N_CLS + cL];
        float kv1 = kern[(kb+1)*N_CLS + cL];
        float kv2 = kern[(kb+2)*N_CLS + cL];
        float kv3 = kern[(kb+3)*N_CLS + cL];
        cn = fmaf(kv0,kv0,cn); cn = fmaf(kv1,kv1,cn);
        cn = fmaf(kv2,kv2,cn); cn = fmaf(kv3,kv3,cn);
        #pragma unroll
        for (int r = 0; r < B_SZ; ++r) {
            const float4 e = *(const float4*)&es[r*D_EMBD + kb];
            acc[r] = fmaf(e.x, kv0, acc[r]);
            acc[r] = fmaf(e.y, kv1, acc[r]);
            acc[r] = fmaf(e.z, kv2, acc[r]);
            acc[r] = fmaf(e.w, kv3, acc[r]);
        }
    }
    __syncthreads();
    #pragma unroll
    for (int r = 0; r < B_SZ; ++r) part[kc*800 + cc*25 + r] = acc[r];
    part[kc*800 + cc*25 + 24] = cn;
    __syncthreads();
    for (int j = t; j < 800; j += 256) {
        float s = 0.f;
        #pragma unroll
        for (int kk = 0; kk < 8; ++kk) s += part[kk*800 + j];
        resb[j] = s;
    }
    __syncthreads();
    for (int o = t; o < 768; o += 256) {
        int r = o >> 5, c2 = o & 31;
        int col = bid*32 + c2;
        if (col >= N_CLS) continue;
        float dot = resb[c2*25 + r];
        float invk = rsqrtf(resb[c2*25 + 24]);
        float cosv = fminf(fmaxf(dot * inv_s[r] * invk, -1.f), 1.f);
        float oc = cosv * S_SCALE;
        float af = oc;
        if (lab_s[r] == col) {
            float tl = cosv;
            float sint = sqrtf(fmaxf(1.f - tl*tl, 0.f));
            float ctm = tl*COS_M - sint*SIN_M;
            float ftl = (tl > TH_C) ? ctm : (tl - MM_C);
            af = ftl * S_SCALE;
        }
        out[r*N_CLS + col] = af;
        out[240001 + r*N_CLS + col] = oc;
    }
}

extern "C" void kernel_launch(void* const* d_in, const int* in_sizes, int n_in,
                              void* d_out, int out_size, void* d_ws, size_t ws_size,
                              hipStream_t stream) {
    (void)in_sizes; (void)n_in; (void)out_size; (void)ws_size;
    const float* emb  = (const float*)d_in[0];
    const float* conv = (const float*)d_in[1];
    const float* kern = (const float*)d_in[2];
    const int*   lab  = (const int*)d_in[3];
    float* out = (float*)d_out;
    float* ws  = (float*)d_ws;
    float* dists = ws;            // 576 floats
    float* Dmat  = ws + 576;      // 576 floats

    k_pairs2<<<348, 512, 0, stream>>>(emb, conv, dists, Dmat);
    k_arc_fin<<<314, 256, 0, stream>>>(emb, kern, lab, dists, Dmat, out);
}

// Round 7
// 618.567 us; speedup vs baseline: 1.0240x; 1.0240x over previous
//
#include <hip/hip_runtime.h>
#include <math.h>

#define B_SZ 24
#define D_EMBD 512
#define N_CLS 10000
#define CC 256
#define HH 196

#define S_SCALE 64.0f
#define COS_M 0.9004471023526769f
#define SIN_M 0.43496553411123023f
#define TH_C (-0.9004471023526769f)
#define MM_C 0.19573449035005357f
#define KSC 14.4269504088896f          /* 10*log2(e) */
#define C2E 0.0693147180559945f        /* eps*ln2 */

#define IMG_STRIDE 57344               /* 7 ksteps * 256 rows * 32 chunks (shorts) */

typedef short bfrag8 __attribute__((ext_vector_type(8)));
typedef float facc4 __attribute__((ext_vector_type(4)));
typedef unsigned int u32;

#if __has_builtin(__builtin_amdgcn_exp2f)
#define EXP2F(x) __builtin_amdgcn_exp2f(x)
#else
#define EXP2F(x) exp2f(x)
#endif
#if __has_builtin(__builtin_amdgcn_logf)
#define LOG2F(x) __builtin_amdgcn_logf(x)
#else
#define LOG2F(x) __log2f(x)
#endif

__device__ inline unsigned short f2bf_rne(float x) {
    union { float f; unsigned u; } cv; cv.f = x;
    unsigned r = cv.u + 0x7FFFu + ((cv.u >> 16) & 1u);
    return (unsigned short)(r >> 16);
}
__device__ inline float bf2f(unsigned short h) {
    union { unsigned u; float f; } cv; cv.u = ((unsigned)h) << 16; return cv.f;
}
__device__ inline float bflo(unsigned u) {
    union { unsigned x; float f; } c; c.x = u << 16; return c.f;
}
__device__ inline float bfhi(unsigned u) {
    union { unsigned x; float f; } c; c.x = u & 0xffff0000u; return c.f;
}
__device__ inline unsigned packbf(float a, float b) {
    return (unsigned)f2bf_rne(a) | ((unsigned)f2bf_rne(b) << 16);
}
// XOR bank swizzle (baked into prep layout; frag reads use same formula)
__device__ inline int swz(int row, int q) {
    return (q ^ (row & 3) ^ ((row >> 2) & 3)) & 3;
}
// async global->LDS, 16B per lane; lds ptr must be wave-uniform (HW adds lane*16)
__device__ __forceinline__ void async16(const void* g, void* l) {
    __builtin_amdgcn_global_load_lds((const __attribute__((address_space(1))) u32*)g,
                                     (__attribute__((address_space(3))) u32*)l, 16, 0, 0);
}

// ================= Launch 1: prep (blocks 0..23) + arcface (blocks 24..180) =================
__global__ __launch_bounds__(512, 2) void k_prep_arc(const float* __restrict__ emb,
        const float* __restrict__ conv, const float* __restrict__ kern,
        const int* __restrict__ label, float* __restrict__ pnorm,
        unsigned short* __restrict__ prep_h, unsigned short* __restrict__ prep_l,
        float* __restrict__ out) {
    const int t = threadIdx.x;
    const int bid = blockIdx.x;

    if (bid < 24) {
        // ---- prep: split-bf16 conversion of image bid into swizzled tile layout ----
        const float* x = conv + bid*CC*HH;
        const int row = t >> 1, half = t & 1;
        const float* xr = x + row*HH;
        float ps = 0.f;
        #pragma unroll 1
        for (int c14 = 0; c14 < 14; ++c14) {
            int kc = half*14 + c14;
            int k = kc*8;
            float v[8];
            if (k + 8 <= HH) {
                const float4* s4 = (const float4*)(xr + k);
                float4 u0 = s4[0], u1 = s4[1];
                v[0]=u0.x; v[1]=u0.y; v[2]=u0.z; v[3]=u0.w;
                v[4]=u1.x; v[5]=u1.y; v[6]=u1.z; v[7]=u1.w;
            } else {
                #pragma unroll
                for (int j = 0; j < 8; ++j) v[j] = (k + j < HH) ? xr[k + j] : 0.f;
            }
            union { unsigned short s[8]; bfrag8 v8; } uh, ul;
            #pragma unroll
            for (int j = 0; j < 8; ++j) {
                ps = fmaf(v[j], v[j], ps);
                unsigned short hb = f2bf_rne(v[j]);
                uh.s[j] = hb;
                ul.s[j] = f2bf_rne(v[j] - bf2f(hb));
            }
            int off = bid*IMG_STRIDE + (kc>>2)*8192 + row*32 + swz(row, kc&3)*8;
            *(bfrag8*)&prep_h[off] = uh.v8;
            *(bfrag8*)&prep_l[off] = ul.v8;
        }
        ps += __shfl_xor(ps, 1, 64);
        if (half == 0) pnorm[bid*CC + row] = ps;
        return;
    }

    // ---- arcface: 64 cols/block, 512 thr ----
    __shared__ __align__(16) float sm[12800];   // es(12288) overlays part(12800); resb in-place
    __shared__ float inv_s[B_SZ];
    __shared__ int lab_s[B_SZ];
    const int ab = bid - 24;

    {
        const float4* s4 = (const float4*)emb;
        float4* d4 = (float4*)sm;
        for (int i = t; i < (B_SZ*D_EMBD)/4; i += 512) d4[i] = s4[i];
    }
    if (t < B_SZ) lab_s[t] = label[t];
    __syncthreads();
    {
        int l = t & 63, w = t >> 6;
        for (int r = w; r < B_SZ; r += 8) {
            float s = 0.f;
            #pragma unroll
            for (int u = 0; u < 8; ++u) { float v = sm[r*D_EMBD + u*64 + l]; s = fmaf(v, v, s); }
            #pragma unroll
            for (int o = 1; o < 64; o <<= 1) s += __shfl_xor(s, o, 64);
            if (l == 0) inv_s[r] = rsqrtf(s);
        }
    }
    __syncthreads();

    const int cc = t & 63, kc = t >> 6;     // 64 cols, 8 k-chunks of 64
    int c = ab*64 + cc;
    int cL = c < N_CLS ? c : N_CLS - 1;
    float acc[B_SZ];
    #pragma unroll
    for (int r = 0; r < B_SZ; ++r) acc[r] = 0.f;
    float cn = 0.f;
    const int k0 = kc*64;
    for (int u = 0; u < 16; ++u) {
        int kb = k0 + u*4;
        float kv0 = kern[(kb+0)*N_CLS + cL];
        float kv1 = kern[(kb+1)*N_CLS + cL];
        float kv2 = kern[(kb+2)*N_CLS + cL];
        float kv3 = kern[(kb+3)*N_CLS + cL];
        cn = fmaf(kv0,kv0,cn); cn = fmaf(kv1,kv1,cn);
        cn = fmaf(kv2,kv2,cn); cn = fmaf(kv3,kv3,cn);
        #pragma unroll
        for (int r = 0; r < B_SZ; ++r) {
            const float4 e = *(const float4*)&sm[r*D_EMBD + kb];
            acc[r] = fmaf(e.x, kv0, acc[r]);
            acc[r] = fmaf(e.y, kv1, acc[r]);
            acc[r] = fmaf(e.z, kv2, acc[r]);
            acc[r] = fmaf(e.w, kv3, acc[r]);
        }
    }
    __syncthreads();   // es reads done before aliased part writes
    #pragma unroll
    for (int r = 0; r < B_SZ; ++r) sm[kc*1600 + cc*25 + r] = acc[r];
    sm[kc*1600 + cc*25 + 24] = cn;
    __syncthreads();
    for (int j = t; j < 1600; j += 512) {
        float s = 0.f;
        #pragma unroll
        for (int kk = 0; kk < 8; ++kk) s += sm[kk*1600 + j];
        sm[j] = s;      // in place: each j owned by exactly one thread
    }
    __syncthreads();
    for (int o = t; o < 1536; o += 512) {
        int r = o >> 6, c2 = o & 63;
        int col = ab*64 + c2;
        if (col >= N_CLS) continue;
        float dot = sm[c2*25 + r];
        float invk = rsqrtf(sm[c2*25 + 24]);
        float cosv = fminf(fmaxf(dot * inv_s[r] * invk, -1.f), 1.f);
        float oc = cosv * S_SCALE;
        float af = oc;
        if (lab_s[r] == col) {
            float tl = cosv;
            float sint = sqrtf(fmaxf(1.f - tl*tl, 0.f));
            float ctm = tl*COS_M - sint*SIN_M;
            float ftl = (tl > TH_C) ? ctm : (tl - MM_C);
            af = ftl * S_SCALE;
        }
        out[r*N_CLS + col] = af;
        out[240001 + r*N_CLS + col] = oc;
    }
}

// ================= Launch 2: pairs (blocks 0..275) + emb gram (276..347) =================
// One (a<b) pair per block, 512 thr. Quarter-tiled 256x256 GEMM with async bf16 staging
// (prep layout => straight 8KB copy/buffer), E packed bf16 in 64 VGPRs, Sinkhorn in reg/LDS.
// __launch_bounds__(512,2): 128-reg budget (R6-measured), 2 blocks/CU.
__global__ __launch_bounds__(512, 2) void k_pairs3(const float* __restrict__ emb,
        const unsigned short* __restrict__ prep_h, const unsigned short* __restrict__ prep_l,
        const float* __restrict__ pnorm, float* __restrict__ dists,
        float* __restrict__ Dmat) {
    const int t = threadIdx.x;
    const int bid = blockIdx.x;

    if (bid >= 276) {
        // ---- emb gram path (no barriers) ----
        int l = t & 63, w16 = t >> 6;
        if (bid == 276 && t < B_SZ) Dmat[t * B_SZ + t] = 0.f;
        int pid = (bid - 276) * 8 + w16;
        if (pid >= B_SZ * B_SZ) return;
        int i = pid / B_SZ, j = pid - (pid / B_SZ) * B_SZ;
        float sij = 0.f, sii = 0.f, sjj = 0.f;
        #pragma unroll
        for (int u = 0; u < 8; ++u) {
            float vi = emb[i*D_EMBD + u*64 + l];
            float vj = emb[j*D_EMBD + u*64 + l];
            sij = fmaf(vi, vj, sij); sii = fmaf(vi, vi, sii); sjj = fmaf(vj, vj, sjj);
        }
        #pragma unroll
        for (int o = 1; o < 64; o <<= 1) {
            sij += __shfl_xor(sij, o, 64);
            sii += __shfl_xor(sii, o, 64);
            sjj += __shfl_xor(sjj, o, 64);
        }
        if (l == 0) dists[pid] = sij * rsqrtf(sii * sjj);
        return;
    }

    __shared__ __align__(16) unsigned short AhS[128*32];   // 8 KB each
    __shared__ __align__(16) unsigned short AlS[128*32];
    __shared__ __align__(16) unsigned short BhS[128*32];
    __shared__ __align__(16) unsigned short BlS[128*32];
    __shared__ __align__(16) float na_s[256];
    __shared__ float nb_s[256];
    __shared__ float rowred[1024];        // quarter: [4][128]; sinkhorn: [4][256]
    __shared__ __align__(16) float rmq[512];   // [ch][global row]
    __shared__ __align__(16) float rm_l[256];
    __shared__ __align__(16) float z_l[256];
    __shared__ float g_l[256];
    __shared__ float colred[512];         // [2][256]
    __shared__ float wredF[4], wredG[4], wredD[8];

    const int w = t >> 6;                  // 0..7
    const int wr2 = w >> 2;                // 0..1 : 64-row group within 128
    const int wc2 = w & 3;                 // 0..3 : 32-col group within 128
    const int q = (t >> 4) & 3, c0 = t & 15;

    // pair index -> (a, b), a < b
    int rem = bid, a = 0;
    while (rem >= 23 - a) { rem -= 23 - a; ++a; }
    int b = a + 1 + rem;

    if (t < 256) {
        na_s[t] = pnorm[a*CC + t];
        nb_s[t] = pnorm[b*CC + t];
    }

    unsigned ue[64];                       // packed bf16 E, 128 elements

    const int istar = ((c0&1)<<3) | ((c0&2)<<1) | ((c0&4)>>1) | ((c0&8)>>3);
    const int rloc_star = wr2*64 + (istar>>2)*16 + q*4 + (istar&3);  // 0..127

    // wave-uniform LDS bases for async staging (HW adds lane*16B)
    unsigned short* lAh = &AhS[(t & ~63) * 8];
    unsigned short* lAl = &AlS[(t & ~63) * 8];
    unsigned short* lBh = &BhS[(t & ~63) * 8];
    unsigned short* lBl = &BlS[(t & ~63) * 8];

    // ---- 4 quarter GEMMs: (rh, ch) over rows rh*128, cols ch*128 ----
    #pragma unroll
    for (int qq = 0; qq < 4; ++qq) {
        const int rh = qq >> 1, ch = qq & 1;
        const unsigned short* gAh = prep_h + (size_t)a*IMG_STRIDE + rh*4096 + t*8;
        const unsigned short* gAl = prep_l + (size_t)a*IMG_STRIDE + rh*4096 + t*8;
        const unsigned short* gBh = prep_h + (size_t)b*IMG_STRIDE + ch*4096 + t*8;
        const unsigned short* gBl = prep_l + (size_t)b*IMG_STRIDE + ch*4096 + t*8;
        facc4 acc[4][2];
        #pragma unroll
        for (int i = 0; i < 4; ++i) { acc[i][0] = (facc4){0,0,0,0}; acc[i][1] = (facc4){0,0,0,0}; }

        #pragma unroll 1
        for (int s = 0; s < 7; ++s) {
            __syncthreads();
            const int so = s*8192;
            async16(gAh + so, lAh);
            async16(gAl + so, lAl);
            async16(gBh + so, lBh);
            async16(gBl + so, lBl);
            __syncthreads();   // drains vmcnt (incl. global_load_lds) before frag reads
            bfrag8 bh2[2], bl2[2];
            #pragma unroll
            for (int tj = 0; tj < 2; ++tj) {
                int col = wc2*32 + tj*16 + c0;
                int cof = col*32 + swz(col, q)*8;
                bh2[tj] = *(const bfrag8*)&BhS[cof];
                bl2[tj] = *(const bfrag8*)&BlS[cof];
            }
            #pragma unroll
            for (int ti = 0; ti < 4; ++ti) {
                int row = wr2*64 + ti*16 + c0;
                int rof = row*32 + swz(row, q)*8;
                bfrag8 ah = *(const bfrag8*)&AhS[rof];
                bfrag8 al = *(const bfrag8*)&AlS[rof];
                #pragma unroll
                for (int tj = 0; tj < 2; ++tj) {
                    acc[ti][tj] = __builtin_amdgcn_mfma_f32_16x16x32_bf16(ah, bh2[tj], acc[ti][tj], 0, 0, 0);
                    acc[ti][tj] = __builtin_amdgcn_mfma_f32_16x16x32_bf16(ah, bl2[tj], acc[ti][tj], 0, 0, 0);
                    acc[ti][tj] = __builtin_amdgcn_mfma_f32_16x16x32_bf16(al, bh2[tj], acc[ti][tj], 0, 0, 0);
                }
            }
        }
        __syncthreads();

        // Ceps2 for the quarter; local row-min over its 128 cols
        facc4 Cv[4][2];
        {
            float nbv[2];
            #pragma unroll
            for (int tj = 0; tj < 2; ++tj) nbv[tj] = nb_s[ch*128 + wc2*32 + tj*16 + c0];
            #pragma unroll
            for (int ti = 0; ti < 4; ++ti) {
                facc4 nav = *(const facc4*)&na_s[rh*128 + wr2*64 + ti*16 + q*4];
                #pragma unroll
                for (int tj = 0; tj < 2; ++tj) {
                    #pragma unroll
                    for (int r = 0; r < 4; ++r) {
                        float d2 = fmaxf(nav[r] + nbv[tj] - 2.f*acc[ti][tj][r], 0.f);
                        Cv[ti][tj][r] = KSC * sqrtf(d2 + 1e-12f);
                    }
                }
            }
        }
        {
            float v16[16];
            #pragma unroll
            for (int ti = 0; ti < 4; ++ti)
                #pragma unroll
                for (int r = 0; r < 4; ++r)
                    v16[ti*4+r] = fminf(Cv[ti][0][r], Cv[ti][1][r]);
            #pragma unroll
            for (int p = 0; p < 4; ++p) {
                const int m = 1 << p, hsz = 8 >> p;
                const bool hi = (c0 >> p) & 1;
                #pragma unroll
                for (int j = 0; j < hsz; ++j) {
                    float mine = hi ? v16[j+hsz] : v16[j];
                    float send = hi ? v16[j] : v16[j+hsz];
                    v16[j] = fminf(mine, __shfl_xor(send, m, 64));
                }
            }
            rowred[wc2*128 + rloc_star] = v16[0];
        }
        __syncthreads();
        if (t < 128) {
            float m = fminf(fminf(rowred[t], rowred[128+t]), fminf(rowred[256+t], rowred[384+t]));
            rmq[ch*256 + rh*128 + t] = m;
        }
        __syncthreads();
        // E_q = 2^(rmq - Ceps2) packed bf16 -> ue[qq*16 ..]
        #pragma unroll
        for (int ti = 0; ti < 4; ++ti) {
            facc4 rmv = *(const facc4*)&rmq[ch*256 + rh*128 + wr2*64 + ti*16 + q*4];
            #pragma unroll
            for (int tj = 0; tj < 2; ++tj) {
                float e0 = EXP2F(rmv[0] - Cv[ti][tj][0]);
                float e1 = EXP2F(rmv[1] - Cv[ti][tj][1]);
                float e2 = EXP2F(rmv[2] - Cv[ti][tj][2]);
                float e3 = EXP2F(rmv[3] - Cv[ti][tj][3]);
                ue[qq*16 + ti*4 + tj*2 + 0] = packbf(e0, e1);
                ue[qq*16 + ti*4 + tj*2 + 1] = packbf(e2, e3);
            }
        }
    }

    // ---- final rm = min over col halves; rescale E exactly (power of 2) ----
    if (t < 256) { rm_l[t] = fminf(rmq[t], rmq[256+t]); g_l[t] = 0.f; }
    if (t < 4) wredG[t] = 0.f;
    __syncthreads();
    #pragma unroll
    for (int rh = 0; rh < 2; ++rh) {
        #pragma unroll
        for (int ti = 0; ti < 4; ++ti) {
            const int rb = rh*128 + wr2*64 + ti*16 + q*4;
            facc4 rmv = *(const facc4*)&rm_l[rb];
            #pragma unroll
            for (int ch = 0; ch < 2; ++ch) {
                facc4 rq = *(const facc4*)&rmq[ch*256 + rb];
                float s0 = EXP2F(rmv[0] - rq[0]);
                float s1 = EXP2F(rmv[1] - rq[1]);
                float s2 = EXP2F(rmv[2] - rq[2]);
                float s3 = EXP2F(rmv[3] - rq[3]);
                #pragma unroll
                for (int tj = 0; tj < 2; ++tj) {
                    const int i0 = (rh*2+ch)*16 + ti*4 + tj*2;
                    unsigned u0 = ue[i0], u1 = ue[i0+1];
                    ue[i0]   = packbf(bflo(u0)*s0, bfhi(u0)*s1);
                    ue[i0+1] = packbf(bflo(u1)*s2, bfhi(u1)*s3);
                }
            }
        }
    }

    // ---- 6 Sinkhorn iterations ----
    #pragma unroll 1
    for (int it = 0; it < 6; ++it) {
        // phase A: row partial sums over this thread's 4 cols
        float Gmax = fmaxf(fmaxf(wredG[0], wredG[1]), fmaxf(wredG[2], wredG[3]));
        float P4[4];
        #pragma unroll
        for (int ch = 0; ch < 2; ++ch)
            #pragma unroll
            for (int tj = 0; tj < 2; ++tj)
                P4[ch*2+tj] = EXP2F(g_l[ch*128 + wc2*32 + tj*16 + c0] - Gmax);
        #pragma unroll
        for (int rh = 0; rh < 2; ++rh) {
            float v16[16];
            #pragma unroll
            for (int ti = 0; ti < 4; ++ti) {
                float s0 = 0.f, s1 = 0.f, s2 = 0.f, s3 = 0.f;
                #pragma unroll
                for (int ch = 0; ch < 2; ++ch)
                    #pragma unroll
                    for (int tj = 0; tj < 2; ++tj) {
                        const int i0 = (rh*2+ch)*16 + ti*4 + tj*2;
                        unsigned u0 = ue[i0], u1 = ue[i0+1];
                        float p = P4[ch*2+tj];
                        s0 = fmaf(bflo(u0), p, s0); s1 = fmaf(bfhi(u0), p, s1);
                        s2 = fmaf(bflo(u1), p, s2); s3 = fmaf(bfhi(u1), p, s3);
                    }
                v16[ti*4+0]=s0; v16[ti*4+1]=s1; v16[ti*4+2]=s2; v16[ti*4+3]=s3;
            }
            #pragma unroll
            for (int p = 0; p < 4; ++p) {
                const int m = 1 << p, hsz = 8 >> p;
                const bool hi = (c0 >> p) & 1;
                #pragma unroll
                for (int j = 0; j < hsz; ++j) {
                    float mine = hi ? v16[j+hsz] : v16[j];
                    float send = hi ? v16[j] : v16[j+hsz];
                    v16[j] = mine + __shfl_xor(send, m, 64);
                }
            }
            rowred[wc2*256 + rh*128 + rloc_star] = v16[0];
        }
        __syncthreads();
        if (t < 256) {
            float s = rowred[t] + rowred[256+t] + rowred[512+t] + rowred[768+t];
            float z = 8.f - Gmax - LOG2F(s);
            z_l[t] = z;
            float m = z;
            #pragma unroll
            for (int o = 1; o < 64; o <<= 1) m = fmaxf(m, __shfl_xor(m, o, 64));
            if ((t & 63) == 0) wredF[t >> 6] = m;
        }
        __syncthreads();
        // phase C: col partial sums over this thread's 32 rows
        float M = fmaxf(fmaxf(wredF[0], wredF[1]), fmaxf(wredF[2], wredF[3]));
        float w4[4] = {0.f, 0.f, 0.f, 0.f};
        #pragma unroll
        for (int rh = 0; rh < 2; ++rh)
            #pragma unroll
            for (int ti = 0; ti < 4; ++ti) {
                facc4 zv = *(const facc4*)&z_l[rh*128 + wr2*64 + ti*16 + q*4];
                float Q0 = EXP2F(zv[0] - M), Q1 = EXP2F(zv[1] - M);
                float Q2 = EXP2F(zv[2] - M), Q3 = EXP2F(zv[3] - M);
                #pragma unroll
                for (int ch = 0; ch < 2; ++ch)
                    #pragma unroll
                    for (int tj = 0; tj < 2; ++tj) {
                        const int i0 = (rh*2+ch)*16 + ti*4 + tj*2;
                        unsigned u0 = ue[i0], u1 = ue[i0+1];
                        float s = w4[ch*2+tj];
                        s = fmaf(bflo(u0), Q0, s); s = fmaf(bfhi(u0), Q1, s);
                        s = fmaf(bflo(u1), Q2, s); s = fmaf(bfhi(u1), Q3, s);
                        w4[ch*2+tj] = s;
                    }
            }
        {   // q-tournament: strides 16, 32; lane q keeps idx = (q&1)*2 + (q>>1)
            #pragma unroll
            for (int p = 0; p < 2; ++p) {
                const int m = 16 << p, hsz = 2 >> p;
                const bool hi = p == 0 ? (q & 1) : ((q >> 1) & 1);
                #pragma unroll
                for (int j = 0; j < hsz; ++j) {
                    float mine = hi ? w4[j+hsz] : w4[j];
                    float send = hi ? w4[j] : w4[j+hsz];
                    w4[j] = mine + __shfl_xor(send, m, 64);
                }
            }
            const int colstar = (q&1)*128 + wc2*32 + (q>>1)*16 + c0;
            colred[wr2*256 + colstar] = w4[0];
        }
        __syncthreads();
        if (t < 256) {
            float s = colred[t] + colred[256+t];
            float G = 8.f - M - LOG2F(s);
            g_l[t] = G;
            float m = G;
            #pragma unroll
            for (int o = 1; o < 64; o <<= 1) m = fmaxf(m, __shfl_xor(m, o, 64));
            if ((t & 63) == 0) wredG[t >> 6] = m;
        }
        __syncthreads();
    }

    // ---- D = sum(T*C): T = 2^(z + G - 16 + log2 E), Ceps2 = rm - log2 E ----
    {
        float G4[4];
        #pragma unroll
        for (int ch = 0; ch < 2; ++ch)
            #pragma unroll
            for (int tj = 0; tj < 2; ++tj)
                G4[ch*2+tj] = g_l[ch*128 + wc2*32 + tj*16 + c0] - 16.f;
        float d = 0.f;
        #pragma unroll
        for (int rh = 0; rh < 2; ++rh)
            #pragma unroll
            for (int ti = 0; ti < 4; ++ti) {
                const int rb = rh*128 + wr2*64 + ti*16 + q*4;
                facc4 zv = *(const facc4*)&z_l[rb];
                facc4 rmv = *(const facc4*)&rm_l[rb];
                #pragma unroll
                for (int ch = 0; ch < 2; ++ch)
                    #pragma unroll
                    for (int tj = 0; tj < 2; ++tj) {
                        const int i0 = (rh*2+ch)*16 + ti*4 + tj*2;
                        unsigned u0 = ue[i0], u1 = ue[i0+1];
                        float gb = G4[ch*2+tj];
                        float e, lE;
                        e = fmaxf(bflo(u0), 1e-38f); lE = LOG2F(e);
                        d = fmaf(EXP2F(zv[0] + gb + lE), rmv[0] - lE, d);
                        e = fmaxf(bfhi(u0), 1e-38f); lE = LOG2F(e);
                        d = fmaf(EXP2F(zv[1] + gb + lE), rmv[1] - lE, d);
                        e = fmaxf(bflo(u1), 1e-38f); lE = LOG2F(e);
                        d = fmaf(EXP2F(zv[2] + gb + lE), rmv[2] - lE, d);
                        e = fmaxf(bfhi(u1), 1e-38f); lE = LOG2F(e);
                        d = fmaf(EXP2F(zv[3] + gb + lE), rmv[3] - lE, d);
                    }
            }
        d *= C2E;
        #pragma unroll
        for (int o = 1; o < 64; o <<= 1) d += __shfl_xor(d, o, 64);
        if ((t & 63) == 0) wredD[w] = d;
        __syncthreads();
        if (t == 0) {
            float s = 0.f;
            #pragma unroll
            for (int i = 0; i < 8; ++i) s += wredD[i];
            Dmat[a*B_SZ + b] = s;
            Dmat[b*B_SZ + a] = s;
        }
    }
}

// ================= Launch 3: triplet scan + scalar outputs =================
__global__ __launch_bounds__(256) void k_fin(const int* __restrict__ label,
        const float* __restrict__ dists, const float* __restrict__ Dmat,
        float* __restrict__ out) {
    const int t = threadIdx.x;
    __shared__ float ds[576], Dm[576];
    __shared__ int lab[B_SZ];
    __shared__ float wls[4]; __shared__ int wnp[4], wot[4];
    for (int i = t; i < 576; i += 256) { ds[i] = dists[i]; Dm[i] = Dmat[i]; }
    if (t < B_SZ) lab[t] = label[t];
    __syncthreads();
    int np = 0, ot = 0; float wsum = 0.f;
    for (int idx = t; idx < 24*24*24; idx += 256) {
        int a2 = idx / 576;
        int rest = idx - a2*576;
        int p2 = rest / 24;
        int n2 = rest - p2*24;
        int la = lab[a2];
        if (la == lab[p2] && la != lab[n2]) {
            float diff = ds[a2*24 + n2] - ds[a2*24 + p2];
            if (diff > 0.f) {
                ++np;
                float dd = Dm[a2*24 + p2] - Dm[a2*24 + n2];
                if (dd > 0.f) { ++ot; wsum += dd; }
            }
        }
    }
    #pragma unroll
    for (int o = 1; o < 64; o <<= 1) {
        np += __shfl_xor(np, o, 64);
        ot += __shfl_xor(ot, o, 64);
        wsum += __shfl_xor(wsum, o, 64);
    }
    int w = t >> 6;
    if ((t & 63) == 0) { wnp[w] = np; wot[w] = ot; wls[w] = wsum; }
    __syncthreads();
    if (t == 0) {
        int tnp = wnp[0]+wnp[1]+wnp[2]+wnp[3];
        int tot = wot[0]+wot[1]+wot[2]+wot[3];
        float tws = wls[0]+wls[1]+wls[2]+wls[3];
        int den = tot > 1 ? tot : 1;
        float wl = (tws > 0.f) ? tws / (float)den : 0.f;
        out[240000] = wl;
        out[480001] = (float)tnp;
        out[480002] = (float)tot;
    }
}

extern "C" void kernel_launch(void* const* d_in, const int* in_sizes, int n_in,
                              void* d_out, int out_size, void* d_ws, size_t ws_size,
                              hipStream_t stream) {
    (void)in_sizes; (void)n_in; (void)out_size; (void)ws_size;
    const float* emb  = (const float*)d_in[0];
    const float* conv = (const float*)d_in[1];
    const float* kern = (const float*)d_in[2];
    const int*   lab  = (const int*)d_in[3];
    float* out = (float*)d_out;
    float* ws  = (float*)d_ws;
    float* dists = ws;                         // 576 floats
    float* Dmat  = ws + 576;                   // 576 floats
    float* pnorm = ws + 1152;                  // 6144 floats
    unsigned short* prep_h = (unsigned short*)(ws + 7296);   // 24*57344 shorts
    unsigned short* prep_l = prep_h + 24*IMG_STRIDE;         // 24*57344 shorts (~5.5 MB total)

    k_prep_arc<<<181, 512, 0, stream>>>(emb, conv, kern, lab, pnorm, prep_h, prep_l, out);
    k_pairs3<<<348, 512, 0, stream>>>(emb, prep_h, prep_l, pnorm, dists, Dmat);
    k_fin<<<1, 256, 0, stream>>>(lab, dists, Dmat, out);
}

// Round 8
// 206.720 us; speedup vs baseline: 3.0641x; 2.9923x over previous
//
#include <hip/hip_runtime.h>
#include <math.h>

#define B_SZ 24
#define D_EMBD 512
#define N_CLS 10000
#define CC 256
#define HH 196

#define S_SCALE 64.0f
#define COS_M 0.9004471023526769f
#define SIN_M 0.43496553411123023f
#define TH_C (-0.9004471023526769f)
#define MM_C 0.19573449035005357f
#define KSC 14.4269504088896f          /* 10*log2(e) */
#define C2E 0.0693147180559945f        /* eps*ln2 */

#define IMG_STRIDE 57344               /* 7 ksteps * 256 rows * 32 chunks (shorts) */

typedef short bfrag8 __attribute__((ext_vector_type(8)));
typedef float facc4 __attribute__((ext_vector_type(4)));
typedef unsigned int u32;

#if __has_builtin(__builtin_amdgcn_exp2f)
#define EXP2F(x) __builtin_amdgcn_exp2f(x)
#else
#define EXP2F(x) exp2f(x)
#endif
#if __has_builtin(__builtin_amdgcn_logf)
#define LOG2F(x) __builtin_amdgcn_logf(x)
#else
#define LOG2F(x) __log2f(x)
#endif

__device__ inline unsigned short f2bf_rne(float x) {
    union { float f; unsigned u; } cv; cv.f = x;
    unsigned r = cv.u + 0x7FFFu + ((cv.u >> 16) & 1u);
    return (unsigned short)(r >> 16);
}
__device__ inline float bf2f(unsigned short h) {
    union { unsigned u; float f; } cv; cv.u = ((unsigned)h) << 16; return cv.f;
}
// XOR bank swizzle (baked into prep layout; frag reads use same formula)
__device__ inline int swz(int row, int q) {
    return (q ^ (row & 3) ^ ((row >> 2) & 3)) & 3;
}
// async global->LDS, 16B per lane; lds ptr must be wave-uniform (HW adds lane*16)
__device__ __forceinline__ void async16(const void* g, void* l) {
    __builtin_amdgcn_global_load_lds((const __attribute__((address_space(1))) u32*)g,
                                     (__attribute__((address_space(3))) u32*)l, 16, 0, 0);
}

// ================= Launch 1: prep (blocks 0..23) + arcface (blocks 24..180) =================
__global__ __launch_bounds__(512, 2) void k_prep_arc(const float* __restrict__ emb,
        const float* __restrict__ conv, const float* __restrict__ kern,
        const int* __restrict__ label, float* __restrict__ pnorm,
        unsigned short* __restrict__ prep_h, unsigned short* __restrict__ prep_l,
        float* __restrict__ out) {
    const int t = threadIdx.x;
    const int bid = blockIdx.x;

    if (bid < 24) {
        // ---- prep: split-bf16 conversion of image bid into swizzled tile layout ----
        const float* x = conv + bid*CC*HH;
        const int row = t >> 1, half = t & 1;
        const float* xr = x + row*HH;
        float ps = 0.f;
        #pragma unroll 1
        for (int c14 = 0; c14 < 14; ++c14) {
            int kc = half*14 + c14;
            int k = kc*8;
            float v[8];
            if (k + 8 <= HH) {
                const float4* s4 = (const float4*)(xr + k);
                float4 u0 = s4[0], u1 = s4[1];
                v[0]=u0.x; v[1]=u0.y; v[2]=u0.z; v[3]=u0.w;
                v[4]=u1.x; v[5]=u1.y; v[6]=u1.z; v[7]=u1.w;
            } else {
                #pragma unroll
                for (int j = 0; j < 8; ++j) v[j] = (k + j < HH) ? xr[k + j] : 0.f;
            }
            union { unsigned short s[8]; bfrag8 v8; } uh, ul;
            #pragma unroll
            for (int j = 0; j < 8; ++j) {
                ps = fmaf(v[j], v[j], ps);
                unsigned short hb = f2bf_rne(v[j]);
                uh.s[j] = hb;
                ul.s[j] = f2bf_rne(v[j] - bf2f(hb));
            }
            int off = bid*IMG_STRIDE + (kc>>2)*8192 + row*32 + swz(row, kc&3)*8;
            *(bfrag8*)&prep_h[off] = uh.v8;
            *(bfrag8*)&prep_l[off] = ul.v8;
        }
        ps += __shfl_xor(ps, 1, 64);
        if (half == 0) pnorm[bid*CC + row] = ps;
        return;
    }

    // ---- arcface: 64 cols/block, 512 thr ----
    __shared__ __align__(16) float sm[12800];   // es(12288) overlays part(12800); resb in-place
    __shared__ float inv_s[B_SZ];
    __shared__ int lab_s[B_SZ];
    const int ab = bid - 24;

    {
        const float4* s4 = (const float4*)emb;
        float4* d4 = (float4*)sm;
        for (int i = t; i < (B_SZ*D_EMBD)/4; i += 512) d4[i] = s4[i];
    }
    if (t < B_SZ) lab_s[t] = label[t];
    __syncthreads();
    {
        int l = t & 63, w = t >> 6;
        for (int r = w; r < B_SZ; r += 8) {
            float s = 0.f;
            #pragma unroll
            for (int u = 0; u < 8; ++u) { float v = sm[r*D_EMBD + u*64 + l]; s = fmaf(v, v, s); }
            #pragma unroll
            for (int o = 1; o < 64; o <<= 1) s += __shfl_xor(s, o, 64);
            if (l == 0) inv_s[r] = rsqrtf(s);
        }
    }
    __syncthreads();

    const int cc = t & 63, kc = t >> 6;     // 64 cols, 8 k-chunks of 64
    int c = ab*64 + cc;
    int cL = c < N_CLS ? c : N_CLS - 1;
    float acc[B_SZ];
    #pragma unroll
    for (int r = 0; r < B_SZ; ++r) acc[r] = 0.f;
    float cn = 0.f;
    const int k0 = kc*64;
    for (int u = 0; u < 16; ++u) {
        int kb = k0 + u*4;
        float kv0 = kern[(kb+0)*N_CLS + cL];
        float kv1 = kern[(kb+1)*N_CLS + cL];
        float kv2 = kern[(kb+2)*N_CLS + cL];
        float kv3 = kern[(kb+3)*N_CLS + cL];
        cn = fmaf(kv0,kv0,cn); cn = fmaf(kv1,kv1,cn);
        cn = fmaf(kv2,kv2,cn); cn = fmaf(kv3,kv3,cn);
        #pragma unroll
        for (int r = 0; r < B_SZ; ++r) {
            const float4 e = *(const float4*)&sm[r*D_EMBD + kb];
            acc[r] = fmaf(e.x, kv0, acc[r]);
            acc[r] = fmaf(e.y, kv1, acc[r]);
            acc[r] = fmaf(e.z, kv2, acc[r]);
            acc[r] = fmaf(e.w, kv3, acc[r]);
        }
    }
    __syncthreads();   // es reads done before aliased part writes
    #pragma unroll
    for (int r = 0; r < B_SZ; ++r) sm[kc*1600 + cc*25 + r] = acc[r];
    sm[kc*1600 + cc*25 + 24] = cn;
    __syncthreads();
    for (int j = t; j < 1600; j += 512) {
        float s = 0.f;
        #pragma unroll
        for (int kk = 0; kk < 8; ++kk) s += sm[kk*1600 + j];
        sm[j] = s;      // in place: each j owned by exactly one thread
    }
    __syncthreads();
    for (int o = t; o < 1536; o += 512) {
        int r = o >> 6, c2 = o & 63;
        int col = ab*64 + c2;
        if (col >= N_CLS) continue;
        float dot = sm[c2*25 + r];
        float invk = rsqrtf(sm[c2*25 + 24]);
        float cosv = fminf(fmaxf(dot * inv_s[r] * invk, -1.f), 1.f);
        float oc = cosv * S_SCALE;
        float af = oc;
        if (lab_s[r] == col) {
            float tl = cosv;
            float sint = sqrtf(fmaxf(1.f - tl*tl, 0.f));
            float ctm = tl*COS_M - sint*SIN_M;
            float ftl = (tl > TH_C) ? ctm : (tl - MM_C);
            af = ftl * S_SCALE;
        }
        out[r*N_CLS + col] = af;
        out[240001 + r*N_CLS + col] = oc;
    }
}

// ================= Launch 2: pairs (blocks 0..275) + emb gram (276..311) =================
// R3's proven 1024-thread monolith (VGPR 64 + acc in AGPRs, zero spill) with async
// staging from prep tiles (no conversion VALU in the K-loop).
__global__ __launch_bounds__(1024) void k_pairs4(const float* __restrict__ emb,
        const unsigned short* __restrict__ prep_h, const unsigned short* __restrict__ prep_l,
        const float* __restrict__ pnorm, float* __restrict__ dists,
        float* __restrict__ Dmat) {
    const int t = threadIdx.x;
    const int bid = blockIdx.x;

    if (bid >= 276) {
        // ---- emb gram path (no barriers) ----
        int l = t & 63, w16 = t >> 6;
        if (bid == 276 && t < B_SZ) Dmat[t * B_SZ + t] = 0.f;
        int pid = (bid - 276) * 16 + w16;
        if (pid >= B_SZ * B_SZ) return;
        int i = pid / B_SZ, j = pid - (pid / B_SZ) * B_SZ;
        float sij = 0.f, sii = 0.f, sjj = 0.f;
        #pragma unroll
        for (int u = 0; u < 8; ++u) {
            float vi = emb[i*D_EMBD + u*64 + l];
            float vj = emb[j*D_EMBD + u*64 + l];
            sij = fmaf(vi, vj, sij); sii = fmaf(vi, vi, sii); sjj = fmaf(vj, vj, sjj);
        }
        #pragma unroll
        for (int o = 1; o < 64; o <<= 1) {
            sij += __shfl_xor(sij, o, 64);
            sii += __shfl_xor(sii, o, 64);
            sjj += __shfl_xor(sjj, o, 64);
        }
        if (l == 0) dists[pid] = sij * rsqrtf(sii * sjj);
        return;
    }

    __shared__ __align__(16) char smem[65536];
    // GEMM overlay: 4 staging buffers [256 rows][32 k] bf16 (16 KB each), swizzled layout
    unsigned short* AhS = (unsigned short*)smem;
    unsigned short* AlS = AhS + 8192;
    unsigned short* BhS = AlS + 8192;
    unsigned short* BlS = BhS + 8192;
    // Sinkhorn overlay (used strictly after GEMM's last fragment-read barrier)
    float* rowred = (float*)smem;        // [4][256]
    float* colred = rowred + 1024;       // [4][256]
    float* rm_l   = colred + 1024;       // [256]
    float* z_l    = rm_l + 256;          // [256]
    float* g_l    = z_l + 256;           // [256]
    float* na_s   = g_l + 256;           // [256]
    float* nb_s   = na_s + 256;          // [256]
    float* wredF  = nb_s + 256;          // [4]
    float* wredG  = wredF + 4;           // [4]
    float* wredD  = wredG + 4;           // [16]

    const int w = t >> 6;
    const int wr = w >> 2, wc = w & 3;
    const int q = (t >> 4) & 3, c0 = t & 15;
    const int R0 = wr * 64, C0 = wc * 64;

    // pair index -> (a, b), a < b
    int rem = bid, a = 0;
    while (rem >= 23 - a) { rem -= 23 - a; ++a; }
    int b = a + 1 + rem;

    const unsigned short* gAh = prep_h + (size_t)a*IMG_STRIDE + t*8;
    const unsigned short* gAl = prep_l + (size_t)a*IMG_STRIDE + t*8;
    const unsigned short* gBh = prep_h + (size_t)b*IMG_STRIDE + t*8;
    const unsigned short* gBl = prep_l + (size_t)b*IMG_STRIDE + t*8;
    // wave-uniform LDS bases (HW adds lane*16B)
    unsigned short* lAh = &AhS[(t & ~63) * 8];
    unsigned short* lAl = &AlS[(t & ~63) * 8];
    unsigned short* lBh = &BhS[(t & ~63) * 8];
    unsigned short* lBl = &BlS[(t & ~63) * 8];

    facc4 acc[4][4];
    #pragma unroll
    for (int i = 0; i < 4; ++i)
        #pragma unroll
        for (int j = 0; j < 4; ++j) acc[i][j] = (facc4){0.f, 0.f, 0.f, 0.f};

    // ---- GEMM: 7 K-steps of 32, async staging of full 256-row tiles ----
    #pragma unroll 1
    for (int s = 0; s < 7; ++s) {
        __syncthreads();
        const int so = s*8192;
        async16(gAh + so, lAh);
        async16(gAl + so, lAl);
        async16(gBh + so, lBh);
        async16(gBl + so, lBl);
        __syncthreads();   // drains vmcnt (incl. global_load_lds) before frag reads
        bfrag8 bh4[4], bl4[4];
        #pragma unroll
        for (int tj = 0; tj < 4; ++tj) {
            int col = C0 + tj*16 + c0;
            int cof = col*32 + swz(col, q)*8;
            bh4[tj] = *(const bfrag8*)&BhS[cof];
            bl4[tj] = *(const bfrag8*)&BlS[cof];
        }
        #pragma unroll
        for (int ti = 0; ti < 4; ++ti) {
            int row = R0 + ti*16 + c0;
            int rof = row*32 + swz(row, q)*8;
            bfrag8 ah = *(const bfrag8*)&AhS[rof];
            bfrag8 al = *(const bfrag8*)&AlS[rof];
            #pragma unroll
            for (int tj = 0; tj < 4; ++tj) {
                acc[ti][tj] = __builtin_amdgcn_mfma_f32_16x16x32_bf16(ah, bh4[tj], acc[ti][tj], 0, 0, 0);
                acc[ti][tj] = __builtin_amdgcn_mfma_f32_16x16x32_bf16(ah, bl4[tj], acc[ti][tj], 0, 0, 0);
                acc[ti][tj] = __builtin_amdgcn_mfma_f32_16x16x32_bf16(al, bh4[tj], acc[ti][tj], 0, 0, 0);
            }
        }
    }
    __syncthreads();   // GEMM frag reads done; LDS reused for Sinkhorn

    if (t < 256) {
        na_s[t] = pnorm[a*CC + t];
        nb_s[t] = pnorm[b*CC + t];
        g_l[t] = 0.f;
    }
    if (t < 4) wredG[t] = 0.f;
    __syncthreads();

    // C/D layout (16x16x32): row = R0 + ti*16 + q*4 + r, col = C0 + tj*16 + c0
    facc4 E[4][4];                        // first Ceps2, then 2^(rm - Ceps2)
    {
        float nbv[4];
        #pragma unroll
        for (int tj = 0; tj < 4; ++tj) nbv[tj] = nb_s[C0 + tj*16 + c0];
        #pragma unroll
        for (int ti = 0; ti < 4; ++ti) {
            facc4 nav = *(const facc4*)&na_s[R0 + ti*16 + q*4];
            #pragma unroll
            for (int tj = 0; tj < 4; ++tj) {
                #pragma unroll
                for (int r = 0; r < 4; ++r) {
                    float d2 = fmaxf(nav[r] + nbv[tj] - 2.f*acc[ti][tj][r], 0.f);
                    E[ti][tj][r] = KSC * sqrtf(d2 + 1e-12f);
                }
            }
        }
    }

    const int istar = ((c0&1)<<3) | ((c0&2)<<1) | ((c0&4)>>1) | ((c0&8)>>3);
    const int rowstar = R0 + (istar>>2)*16 + q*4 + (istar&3);
    const int tjstar = ((q&1)<<1) | (q>>1);
    const int colstar = C0 + tjstar*16 + c0;

    {
        float v16[16];
        #pragma unroll
        for (int ti = 0; ti < 4; ++ti)
            #pragma unroll
            for (int r = 0; r < 4; ++r)
                v16[ti*4+r] = fminf(fminf(E[ti][0][r], E[ti][1][r]),
                                    fminf(E[ti][2][r], E[ti][3][r]));
        #pragma unroll
        for (int p = 0; p < 4; ++p) {
            const int m = 1 << p, hsz = 8 >> p;
            const bool hi = (c0 >> p) & 1;
            #pragma unroll
            for (int j = 0; j < hsz; ++j) {
                float mine = hi ? v16[j+hsz] : v16[j];
                float send = hi ? v16[j] : v16[j+hsz];
                v16[j] = fminf(mine, __shfl_xor(send, m, 64));
            }
        }
        rowred[wc*256 + rowstar] = v16[0];
    }
    __syncthreads();
    if (t < 256)
        rm_l[t] = fminf(fminf(rowred[t], rowred[256+t]), fminf(rowred[512+t], rowred[768+t]));
    __syncthreads();

    #pragma unroll
    for (int ti = 0; ti < 4; ++ti) {
        facc4 rmv = *(const facc4*)&rm_l[R0 + ti*16 + q*4];
        #pragma unroll
        for (int tj = 0; tj < 4; ++tj)
            #pragma unroll
            for (int r = 0; r < 4; ++r)
                E[ti][tj][r] = EXP2F(rmv[r] - E[ti][tj][r]);
    }

    // ---- 6 Sinkhorn iterations (FMA inner loops) ----
    #pragma unroll 1
    for (int it = 0; it < 6; ++it) {
        float Gmax = fmaxf(fmaxf(wredG[0], wredG[1]), fmaxf(wredG[2], wredG[3]));
        float P4[4];
        #pragma unroll
        for (int tj = 0; tj < 4; ++tj) P4[tj] = EXP2F(g_l[C0 + tj*16 + c0] - Gmax);
        float v16[16];
        #pragma unroll
        for (int ti = 0; ti < 4; ++ti)
            #pragma unroll
            for (int r = 0; r < 4; ++r) {
                float s = 0.f;
                #pragma unroll
                for (int tj = 0; tj < 4; ++tj) s = fmaf(E[ti][tj][r], P4[tj], s);
                v16[ti*4+r] = s;
            }
        #pragma unroll
        for (int p = 0; p < 4; ++p) {
            const int m = 1 << p, hsz = 8 >> p;
            const bool hi = (c0 >> p) & 1;
            #pragma unroll
            for (int j = 0; j < hsz; ++j) {
                float mine = hi ? v16[j+hsz] : v16[j];
                float send = hi ? v16[j] : v16[j+hsz];
                v16[j] = mine + __shfl_xor(send, m, 64);
            }
        }
        rowred[wc*256 + rowstar] = v16[0];
        __syncthreads();
        if (t < 256) {
            float s = rowred[t] + rowred[256+t] + rowred[512+t] + rowred[768+t];
            float z = 8.f - Gmax - LOG2F(s);
            z_l[t] = z;
            float m = z;
            #pragma unroll
            for (int o = 1; o < 64; o <<= 1) m = fmaxf(m, __shfl_xor(m, o, 64));
            if ((t & 63) == 0) wredF[t >> 6] = m;
        }
        __syncthreads();
        float M = fmaxf(fmaxf(wredF[0], wredF[1]), fmaxf(wredF[2], wredF[3]));
        float Q[16];
        #pragma unroll
        for (int ti = 0; ti < 4; ++ti) {
            facc4 zv = *(const facc4*)&z_l[R0 + ti*16 + q*4];
            #pragma unroll
            for (int r = 0; r < 4; ++r) Q[ti*4+r] = EXP2F(zv[r] - M);
        }
        float w4[4];
        #pragma unroll
        for (int tj = 0; tj < 4; ++tj) {
            float s = 0.f;
            #pragma unroll
            for (int ti = 0; ti < 4; ++ti)
                #pragma unroll
                for (int r = 0; r < 4; ++r) s = fmaf(E[ti][tj][r], Q[ti*4+r], s);
            w4[tj] = s;
        }
        #pragma unroll
        for (int p = 0; p < 2; ++p) {
            const int m = 16 << p, hsz = 2 >> p;
            const bool hi = (q >> p) & 1;
            #pragma unroll
            for (int j = 0; j < hsz; ++j) {
                float mine = hi ? w4[j+hsz] : w4[j];
                float send = hi ? w4[j] : w4[j+hsz];
                w4[j] = mine + __shfl_xor(send, m, 64);
            }
        }
        colred[wr*256 + colstar] = w4[0];
        __syncthreads();
        if (t < 256) {
            float s = colred[t] + colred[256+t] + colred[512+t] + colred[768+t];
            float G = 8.f - M - LOG2F(s);
            g_l[t] = G;
            float m = G;
            #pragma unroll
            for (int o = 1; o < 64; o <<= 1) m = fmaxf(m, __shfl_xor(m, o, 64));
            if ((t & 63) == 0) wredG[t >> 6] = m;
        }
        __syncthreads();
    }

    // ---- D = sum(T*C): T = 2^(z + G - 16 + log2 E), Ceps2 = rm - log2 E ----
    {
        float G4[4];
        #pragma unroll
        for (int tj = 0; tj < 4; ++tj) G4[tj] = g_l[C0 + tj*16 + c0] - 16.f;
        float d = 0.f;
        #pragma unroll
        for (int ti = 0; ti < 4; ++ti) {
            facc4 zv = *(const facc4*)&z_l[R0 + ti*16 + q*4];
            facc4 rmv = *(const facc4*)&rm_l[R0 + ti*16 + q*4];
            #pragma unroll
            for (int tj = 0; tj < 4; ++tj) {
                #pragma unroll
                for (int r = 0; r < 4; ++r) {
                    float e = fmaxf(E[ti][tj][r], 1e-45f);
                    float lE = LOG2F(e);
                    d = fmaf(EXP2F(zv[r] + G4[tj] + lE), rmv[r] - lE, d);
                }
            }
        }
        d *= C2E;
        #pragma unroll
        for (int o = 1; o < 64; o <<= 1) d += __shfl_xor(d, o, 64);
        if ((t & 63) == 0) wredD[w] = d;
        __syncthreads();
        if (t == 0) {
            float s = 0.f;
            #pragma unroll
            for (int i = 0; i < 16; ++i) s += wredD[i];
            Dmat[a*B_SZ + b] = s;
            Dmat[b*B_SZ + a] = s;
        }
    }
}

// ================= Launch 3: triplet scan + scalar outputs =================
__global__ __launch_bounds__(256) void k_fin(const int* __restrict__ label,
        const float* __restrict__ dists, const float* __restrict__ Dmat,
        float* __restrict__ out) {
    const int t = threadIdx.x;
    __shared__ float ds[576], Dm[576];
    __shared__ int lab[B_SZ];
    __shared__ float wls[4]; __shared__ int wnp[4], wot[4];
    for (int i = t; i < 576; i += 256) { ds[i] = dists[i]; Dm[i] = Dmat[i]; }
    if (t < B_SZ) lab[t] = label[t];
    __syncthreads();
    int np = 0, ot = 0; float wsum = 0.f;
    for (int idx = t; idx < 24*24*24; idx += 256) {
        int a2 = idx / 576;
        int rest = idx - a2*576;
        int p2 = rest / 24;
        int n2 = rest - p2*24;
        int la = lab[a2];
        if (la == lab[p2] && la != lab[n2]) {
            float diff = ds[a2*24 + n2] - ds[a2*24 + p2];
            if (diff > 0.f) {
                ++np;
                float dd = Dm[a2*24 + p2] - Dm[a2*24 + n2];
                if (dd > 0.f) { ++ot; wsum += dd; }
            }
        }
    }
    #pragma unroll
    for (int o = 1; o < 64; o <<= 1) {
        np += __shfl_xor(np, o, 64);
        ot += __shfl_xor(ot, o, 64);
        wsum += __shfl_xor(wsum, o, 64);
    }
    int w = t >> 6;
    if ((t & 63) == 0) { wnp[w] = np; wot[w] = ot; wls[w] = wsum; }
    __syncthreads();
    if (t == 0) {
        int tnp = wnp[0]+wnp[1]+wnp[2]+wnp[3];
        int tot = wot[0]+wot[1]+wot[2]+wot[3];
        float tws = wls[0]+wls[1]+wls[2]+wls[3];
        int den = tot > 1 ? tot : 1;
        float wl = (tws > 0.f) ? tws / (float)den : 0.f;
        out[240000] = wl;
        out[480001] = (float)tnp;
        out[480002] = (float)tot;
    }
}

extern "C" void kernel_launch(void* const* d_in, const int* in_sizes, int n_in,
                              void* d_out, int out_size, void* d_ws, size_t ws_size,
                              hipStream_t stream) {
    (void)in_sizes; (void)n_in; (void)out_size; (void)ws_size;
    const float* emb  = (const float*)d_in[0];
    const float* conv = (const float*)d_in[1];
    const float* kern = (const float*)d_in[2];
    const int*   lab  = (const int*)d_in[3];
    float* out = (float*)d_out;
    float* ws  = (float*)d_ws;
    float* dists = ws;                         // 576 floats
    float* Dmat  = ws + 576;                   // 576 floats
    float* pnorm = ws + 1152;                  // 6144 floats
    unsigned short* prep_h = (unsigned short*)(ws + 7296);   // 24*57344 shorts
    unsigned short* prep_l = prep_h + 24*IMG_STRIDE;         // 24*57344 shorts (~5.5 MB total)

    k_prep_arc<<<181, 512, 0, stream>>>(emb, conv, kern, lab, pnorm, prep_h, prep_l, out);
    k_pairs4<<<312, 1024, 0, stream>>>(emb, prep_h, prep_l, pnorm, dists, Dmat);
    k_fin<<<1, 256, 0, stream>>>(lab, dists, Dmat, out);
}